// Round 3
// baseline (630.670 us; speedup 1.0000x reference)
//
#include <hip/hip_runtime.h>
#include <hip/hip_bf16.h>
#include <cstdint>
#include <cstddef>

// MotionNet decoder: B=16384, STATE=524, IENC=256, ZD=32, H=256, E=5, HG=256
// Round 3: inputs may be fp32 (per harness contract) or bf16 — detect the
// storage format on-device from bit statistics and canonicalize everything
// to bf16 ws buffers. Compute: bf16 MFMA 16x16x32, fp32 accumulation.

#define BATCH 16384

typedef __attribute__((ext_vector_type(8))) short short8;  // 8 bf16 (4 VGPRs)
typedef __attribute__((ext_vector_type(4))) float f32x4;   // MFMA accumulator
typedef unsigned short u16;
typedef unsigned int u32;

__device__ __forceinline__ float bf2f(u16 u) {
  union { float f; u32 i; } v; v.i = ((u32)u) << 16; return v.f;
}
__device__ __forceinline__ u16 f2bf(float f) {
  union { float f; u32 i; } v; v.f = f;
  u32 x = v.i;
  return (u16)((x + 0x7fffu + ((x >> 16) & 1u)) >> 16);  // RNE
}
__device__ __forceinline__ u16 load_bf(const void* p, long i, int f32) {
  return f32 ? f2bf(((const float*)p)[i]) : ((const u16*)p)[i];
}
__device__ __forceinline__ float elu_f(float x) { return x > 0.f ? x : expm1f(x); }

// ---------------------------------------------------------------------------
// dtype detection: for bf16-pair storage, word bits 7..14 are the low bf16's
// exponent (concentrated near 127 for N(0,1) z). For fp32 storage they are
// mantissa bits (uniform). flag: 1 = fp32 storage, 0 = bf16 storage.
// ---------------------------------------------------------------------------
__global__ __launch_bounds__(256) void detect_dtype(const u32* __restrict__ zr,
                                                    int* __restrict__ flag)
{
  __shared__ int cnt;
  if (threadIdx.x == 0) cnt = 0;
  __syncthreads();
  u32 w = zr[threadIdx.x];               // safe: z >= 1 KiB in either dtype
  int e = (w >> 7) & 0xFF;
  if (e >= 112 && e <= 142) atomicAdd(&cnt, 1);
  __syncthreads();
  if (threadIdx.x == 0) *flag = (cnt < 128) ? 1 : 0;
}

// ---------------------------------------------------------------------------
// prep: h0[B,832] = [z(32) | p_prev(524) | (ienc, by inet3) | 0-pad(20)]
//       h1cat/h2cat[B,288] cols 0..31 = z
// Also canonicalizes all small tensors (biases + gw3) into smallc:
//   [0]ib1(256) [256]ib2(256) [512]ib3(256) [768]gb1(256) [1024]gb2(128)
//   [1152]gb3(5,pad to 128) [1280]gw3(640) [1920]bl1(1280) [3200]bl2(1280)
//   [4480]bl3(2620)   -> total 7100
// ---------------------------------------------------------------------------
__global__ __launch_bounds__(256) void prep_kernel(
    const void* __restrict__ z, const void* __restrict__ p,
    const int* __restrict__ flagp,
    u16* __restrict__ h0, u16* __restrict__ h1c, u16* __restrict__ h2c,
    const void* ib1, const void* ib2, const void* ib3,
    const void* gb1, const void* gb2, const void* gb3,
    const void* gw3, const void* bl1, const void* bl2, const void* bl3,
    u16* __restrict__ smallc)
{
  const int f32 = *flagp;
  const long gid0 = (long)blockIdx.x * blockDim.x + threadIdx.x;
  if (gid0 < 7100) {
    long j = gid0; u16 v;
    if      (j < 256)  v = load_bf(ib1, j,        f32);
    else if (j < 512)  v = load_bf(ib2, j - 256,  f32);
    else if (j < 768)  v = load_bf(ib3, j - 512,  f32);
    else if (j < 1024) v = load_bf(gb1, j - 768,  f32);
    else if (j < 1152) v = load_bf(gb2, j - 1024, f32);
    else if (j < 1280) v = (j - 1152 < 5) ? load_bf(gb3, j - 1152, f32) : (u16)0;
    else if (j < 1920) v = load_bf(gw3, j - 1280, f32);
    else if (j < 3200) v = load_bf(bl1, j - 1920, f32);
    else if (j < 4480) v = load_bf(bl2, j - 3200, f32);
    else               v = load_bf(bl3, j - 4480, f32);
    smallc[j] = v;
  }
  const long total = (long)BATCH * 832;
  const long stride = (long)gridDim.x * blockDim.x;
  for (long i = gid0; i < total; i += stride) {
    int b = (int)(i / 832);
    int c = (int)(i - (long)b * 832);
    if (c < 32) {
      u16 v = load_bf(z, (long)b * 32 + c, f32);
      h0[i] = v;
      h1c[(long)b * 288 + c] = v;
      h2c[(long)b * 288 + c] = v;
    } else if (c < 556) {
      h0[i] = load_bf(p, (long)b * 524 + (c - 32), f32);
    } else if (c >= 812) {
      h0[i] = 0;
    }
  }
}

// ---------------------------------------------------------------------------
// I[B,2048] -> canonical bf16, vectorized 8 elements/thread
// ---------------------------------------------------------------------------
__global__ __launch_bounds__(256) void convert_I(
    const void* __restrict__ I, const int* __restrict__ flagp,
    u16* __restrict__ out)
{
  const int f32 = *flagp;
  const long total8 = (long)BATCH * 2048 / 8;
  const long stride = (long)gridDim.x * blockDim.x;
  for (long t = (long)blockIdx.x * blockDim.x + threadIdx.x; t < total8; t += stride) {
    if (f32) {
      const float4* src = (const float4*)I;
      float4 a = src[t * 2], b = src[t * 2 + 1];
      union { u16 r[8]; uint4 v; } u;
      u.r[0] = f2bf(a.x); u.r[1] = f2bf(a.y); u.r[2] = f2bf(a.z); u.r[3] = f2bf(a.w);
      u.r[4] = f2bf(b.x); u.r[5] = f2bf(b.y); u.r[6] = f2bf(b.z); u.r[7] = f2bf(b.w);
      *(uint4*)(out + t * 8) = u.v;
    } else {
      *(uint4*)(out + t * 8) = ((const uint4*)I)[t];
    }
  }
}

// ---------------------------------------------------------------------------
// transpose + pad (+dtype decode): out[e][n][k] = in[e][k][n] or 0-pad
// ---------------------------------------------------------------------------
__global__ __launch_bounds__(256) void transpose_pad(
    const void* __restrict__ in, const int* __restrict__ flagp,
    u16* __restrict__ out, int E, int K, int N, int Kp, int Np)
{
  const int f32 = *flagp;
  const long total = (long)E * Np * Kp;
  const long stride = (long)gridDim.x * blockDim.x;
  for (long i = (long)blockIdx.x * blockDim.x + threadIdx.x; i < total; i += stride) {
    int k = (int)(i % Kp);
    long t = i / Kp;
    int n = (int)(t % Np);
    int e = (int)(t / Np);
    u16 v = 0;
    if (k < K && n < N) v = load_bf(in, (long)e * K * N + (long)k * N + n, f32);
    out[i] = v;
  }
}

// ---------------------------------------------------------------------------
// Generic GEMM: C[M,N] = elu(A[M,K] @ W[K,N] + bias), W transposed [N][K].
// Block tile 128x128, 4 waves 2x2, wave tile 64x64 = 4x4 MFMA 16x16x32.
// All operands canonical bf16. K,lda,ldw %32==0; grid=(M/128, N/128).
// ---------------------------------------------------------------------------
template<bool ELU>
__global__ __launch_bounds__(256) void gemm128(
    const u16* __restrict__ A, int lda,
    const u16* __restrict__ Wt, int ldw,
    const u16* __restrict__ bias,
    u16* __restrict__ C, int ldc, int col_off, int K)
{
  constexpr int LDSK = 40;  // 32 + 8 pad -> max 2-way bank aliasing (free, m136)
  __shared__ __align__(16) u16 sA[128 * LDSK];
  __shared__ __align__(16) u16 sB[128 * LDSK];

  const int tid  = threadIdx.x;
  const int bm   = blockIdx.x, bn = blockIdx.y;
  const int lane = tid & 63, wave = tid >> 6;
  const int wm = (wave & 1) * 64, wn = (wave >> 1) * 64;
  const int lrow = lane & 15, lq = lane >> 4;

  const int srow = tid >> 2;            // 0..63
  const int schunk = (tid & 3) * 8;     // 0,8,16,24

  const u16* Ag = A  + (size_t)(bm * 128) * lda;
  const u16* Wg = Wt + (size_t)(bn * 128) * ldw;

  f32x4 acc[4][4] = {};

  for (int k0 = 0; k0 < K; k0 += 32) {
    __syncthreads();
    {
      uint4 a0 = *(const uint4*)(Ag + (size_t)srow * lda + k0 + schunk);
      uint4 a1 = *(const uint4*)(Ag + (size_t)(srow + 64) * lda + k0 + schunk);
      uint4 b0 = *(const uint4*)(Wg + (size_t)srow * ldw + k0 + schunk);
      uint4 b1 = *(const uint4*)(Wg + (size_t)(srow + 64) * ldw + k0 + schunk);
      *(uint4*)(sA + srow * LDSK + schunk) = a0;
      *(uint4*)(sA + (srow + 64) * LDSK + schunk) = a1;
      *(uint4*)(sB + srow * LDSK + schunk) = b0;
      *(uint4*)(sB + (srow + 64) * LDSK + schunk) = b1;
    }
    __syncthreads();

    short8 a[4], b[4];
#pragma unroll
    for (int i = 0; i < 4; ++i)
      a[i] = *(const short8*)(sA + (wm + i * 16 + lrow) * LDSK + lq * 8);
#pragma unroll
    for (int i = 0; i < 4; ++i)
      b[i] = *(const short8*)(sB + (wn + i * 16 + lrow) * LDSK + lq * 8);

#pragma unroll
    for (int mi = 0; mi < 4; ++mi)
#pragma unroll
      for (int ni = 0; ni < 4; ++ni)
        acc[mi][ni] = __builtin_amdgcn_mfma_f32_16x16x32_bf16(a[mi], b[ni], acc[mi][ni], 0, 0, 0);
  }

#pragma unroll
  for (int ni = 0; ni < 4; ++ni) {
    const int col = bn * 128 + wn + ni * 16 + lrow;
    const float bv = bf2f(bias[col]);
#pragma unroll
    for (int mi = 0; mi < 4; ++mi) {
#pragma unroll
      for (int r = 0; r < 4; ++r) {
        const int row = bm * 128 + wm + mi * 16 + lq * 4 + r;
        float v = acc[mi][ni][r] + bv;
        if (ELU) v = elu_f(v);
        C[(size_t)row * ldc + col_off + col] = f2bf(v);
      }
    }
  }
}

// ---------------------------------------------------------------------------
// gating layer 3 + softmax: omega[B,5] (fp32) = softmax(g2[B,128]@gw3 + gb3)
// one wave per row; gw3c/gb3c canonical bf16
// ---------------------------------------------------------------------------
__global__ __launch_bounds__(256) void gating3_kernel(
    const u16* __restrict__ g2, const u16* __restrict__ gw3c,
    const u16* __restrict__ gb3c, float* __restrict__ omega)
{
  const int wid  = (blockIdx.x << 2) + (threadIdx.x >> 6);
  const int lane = threadIdx.x & 63;
  const u32 gp = *(const u32*)(g2 + (size_t)wid * 128 + lane * 2);
  const float x0 = bf2f((u16)(gp & 0xffffu));
  const float x1 = bf2f((u16)(gp >> 16));
  float acc[5];
#pragma unroll
  for (int e = 0; e < 5; ++e)
    acc[e] = x0 * bf2f(gw3c[(lane * 2) * 5 + e]) + x1 * bf2f(gw3c[(lane * 2 + 1) * 5 + e]);
#pragma unroll
  for (int off = 1; off < 64; off <<= 1) {
#pragma unroll
    for (int e = 0; e < 5; ++e) acc[e] += __shfl_xor(acc[e], off);
  }
  if (lane == 0) {
    float t[5], m = -1e30f;
#pragma unroll
    for (int e = 0; e < 5; ++e) { t[e] = acc[e] + bf2f(gb3c[e]); m = fmaxf(m, t[e]); }
    float s = 0.f;
#pragma unroll
    for (int e = 0; e < 5; ++e) { t[e] = expf(t[e] - m); s += t[e]; }
    const float inv = 1.f / s;
#pragma unroll
    for (int e = 0; e < 5; ++e) omega[(size_t)wid * 5 + e] = t[e] * inv;
  }
}

// ---------------------------------------------------------------------------
// MoE GEMM: out[b,n] = act( sum_e omega[b,e] * ((A@W_e)[n] + bias_e[n]) )
// Expert loop INSIDE K loop: A tile staged once, reused by 5 experts.
// Block 64x64, waves 2x2, wave tile 32x32 = 2x2 MFMA per expert.
// is_final: output store branches fp32/bf16 on *flagp (uniform branch).
// ---------------------------------------------------------------------------
template<bool ELU>
__global__ __launch_bounds__(256) void moe_gemm(
    const u16* __restrict__ A, int lda,
    const u16* __restrict__ Wt, int ldw, long wstride_e,
    const u16* __restrict__ bias, int bias_n,
    const float* __restrict__ omega,
    void* __restrict__ C, int ldc, int col_off, int n_store, int K,
    const int* __restrict__ flagp, int is_final)
{
  constexpr int LDSK = 40;
  __shared__ __align__(16) u16 sA[64 * LDSK];
  __shared__ __align__(16) u16 sW[5][64 * LDSK];
  __shared__ float som[64 * 5];
  __shared__ float sbias[5][64];

  const int tid  = threadIdx.x;
  const int bm   = blockIdx.x, bn = blockIdx.y;
  const int lane = tid & 63, wave = tid >> 6;
  const int wm = (wave & 1) * 32, wn = (wave >> 1) * 32;
  const int lrow = lane & 15, lq = lane >> 4;
  const int f32out = is_final ? *flagp : 0;

  // 320 items on 256 threads: strided loop (round-1 bug was `if (tid<320)`)
  for (int t = tid; t < 320; t += 256) {
    som[t] = omega[(size_t)(bm * 64) * 5 + t];
    const int e = t >> 6, c = t & 63;
    const int col = bn * 64 + c;
    sbias[e][c] = (col < bias_n) ? bf2f(bias[(size_t)e * bias_n + col]) : 0.f;
  }

  const int srow = tid >> 2;           // 0..63
  const int schunk = (tid & 3) * 8;

  const u16* Ag = A  + (size_t)(bm * 64) * lda;
  const u16* Wg = Wt + (size_t)(bn * 64) * ldw;

  f32x4 acc[5][2][2] = {};

  for (int k0 = 0; k0 < K; k0 += 32) {
    __syncthreads();
    *(uint4*)(sA + srow * LDSK + schunk) =
        *(const uint4*)(Ag + (size_t)srow * lda + k0 + schunk);
#pragma unroll
    for (int e = 0; e < 5; ++e)
      *(uint4*)(sW[e] + srow * LDSK + schunk) =
          *(const uint4*)(Wg + e * wstride_e + (size_t)srow * ldw + k0 + schunk);
    __syncthreads();

    short8 a0 = *(const short8*)(sA + (wm + lrow) * LDSK + lq * 8);
    short8 a1 = *(const short8*)(sA + (wm + 16 + lrow) * LDSK + lq * 8);
#pragma unroll
    for (int e = 0; e < 5; ++e) {
      short8 b0 = *(const short8*)(sW[e] + (wn + lrow) * LDSK + lq * 8);
      short8 b1 = *(const short8*)(sW[e] + (wn + 16 + lrow) * LDSK + lq * 8);
      acc[e][0][0] = __builtin_amdgcn_mfma_f32_16x16x32_bf16(a0, b0, acc[e][0][0], 0, 0, 0);
      acc[e][0][1] = __builtin_amdgcn_mfma_f32_16x16x32_bf16(a0, b1, acc[e][0][1], 0, 0, 0);
      acc[e][1][0] = __builtin_amdgcn_mfma_f32_16x16x32_bf16(a1, b0, acc[e][1][0], 0, 0, 0);
      acc[e][1][1] = __builtin_amdgcn_mfma_f32_16x16x32_bf16(a1, b1, acc[e][1][1], 0, 0, 0);
    }
  }

#pragma unroll
  for (int mi = 0; mi < 2; ++mi) {
#pragma unroll
    for (int r = 0; r < 4; ++r) {
      const int rl = wm + mi * 16 + lq * 4 + r;
      const int row = bm * 64 + rl;
      float om[5];
#pragma unroll
      for (int e = 0; e < 5; ++e) om[e] = som[rl * 5 + e];
#pragma unroll
      for (int ni = 0; ni < 2; ++ni) {
        const int c = wn + ni * 16 + lrow;
        const int col = bn * 64 + c;
        if (col < n_store) {
          float v = 0.f;
#pragma unroll
          for (int e = 0; e < 5; ++e) v += om[e] * (acc[e][mi][ni][r] + sbias[e][c]);
          if (ELU) v = elu_f(v);
          const size_t idx = (size_t)row * ldc + col_off + col;
          if (f32out) ((float*)C)[idx] = v;
          else        ((u16*)C)[idx]   = f2bf(v);
        }
      }
    }
  }
}

// ---------------------------------------------------------------------------
static inline int tblocks(long total) {
  long b = (total + 255) / 256;
  return (int)(b < 2048 ? b : 2048);
}

extern "C" void kernel_launch(void* const* d_in, const int* in_sizes, int n_in,
                              void* d_out, int out_size, void* d_ws, size_t ws_size,
                              hipStream_t stream)
{
  const void* z    = d_in[0];
  const void* pprev= d_in[1];
  const void* I    = d_in[2];
  const void* gw1  = d_in[3];
  const void* gb1  = d_in[4];
  const void* gw2  = d_in[5];
  const void* gb2  = d_in[6];
  const void* gw3  = d_in[7];
  const void* gb3  = d_in[8];
  const void* iw1  = d_in[9];
  const void* ib1  = d_in[10];
  const void* ib2  = d_in[12];
  const void* iw2  = d_in[11];
  const void* iw3  = d_in[13];
  const void* ib3  = d_in[14];
  const void* wl1  = d_in[15];
  const void* bl1  = d_in[16];
  const void* wl2  = d_in[17];
  const void* bl2  = d_in[18];
  const void* wl3  = d_in[19];
  const void* bl3  = d_in[20];

  char* base = (char*)d_ws;
  size_t off = 0;
  auto alloc = [&](size_t bytes) -> void* {
    void* p = base + off;
    off = (off + bytes + 255) & ~(size_t)255;
    return p;
  };

  const size_t B = BATCH;
  int* flagp   = (int*)alloc(256);
  u16* h0      = (u16*)alloc(B * 832 * 2);   // [z | p_prev | ienc | pad0]
  u16* h1c     = (u16*)alloc(B * 288 * 2);   // [z | h1]
  u16* h2c     = (u16*)alloc(B * 288 * 2);   // [z | h2]
  u16* i1      = (u16*)alloc(B * 256 * 2);
  u16* i2      = (u16*)alloc(B * 256 * 2);
  float* omega = (float*)alloc(B * 5 * 4);
  u16* Ibf     = (u16*)alloc(B * 2048 * 2);
  u16* smallc  = (u16*)alloc(7100 * 2);
  u16* iw1t = (u16*)alloc((size_t)256 * 2048 * 2);
  u16* iw2t = (u16*)alloc((size_t)256 * 256 * 2);
  u16* iw3t = (u16*)alloc((size_t)256 * 256 * 2);
  u16* gw1t = (u16*)alloc((size_t)256 * 576 * 2);
  u16* gw2t = (u16*)alloc((size_t)128 * 256 * 2);
  u16* wl1t = (u16*)alloc((size_t)5 * 256 * 832 * 2);
  u16* wl2t = (u16*)alloc((size_t)5 * 256 * 288 * 2);
  u16* wl3t = (u16*)alloc((size_t)5 * 576 * 288 * 2);
  u16* g1 = i1;  // INet temporaries dead by gating time
  u16* g2 = i2;
  (void)in_sizes; (void)n_in; (void)out_size; (void)ws_size;

  // canonical small-tensor offsets (see prep_kernel)
  u16* ib1c = smallc + 0,   *ib2c = smallc + 256, *ib3c = smallc + 512;
  u16* gb1c = smallc + 768, *gb2c = smallc + 1024, *gb3c = smallc + 1152;
  u16* gw3c = smallc + 1280;
  u16* bl1c = smallc + 1920, *bl2c = smallc + 3200, *bl3c = smallc + 4480;

  // ---- dtype detect + canonicalize ----
  detect_dtype<<<1, 256, 0, stream>>>((const u32*)z, flagp);
  prep_kernel<<<4096, 256, 0, stream>>>(z, pprev, flagp, h0, h1c, h2c,
      ib1, ib2, ib3, gb1, gb2, gb3, gw3, bl1, bl2, bl3, smallc);
  convert_I<<<4096, 256, 0, stream>>>(I, flagp, Ibf);
  transpose_pad<<<tblocks((long)1*256*2048), 256, 0, stream>>>(iw1, flagp, iw1t, 1, 2048, 256, 2048, 256);
  transpose_pad<<<tblocks((long)1*256*256),  256, 0, stream>>>(iw2, flagp, iw2t, 1, 256, 256, 256, 256);
  transpose_pad<<<tblocks((long)1*256*256),  256, 0, stream>>>(iw3, flagp, iw3t, 1, 256, 256, 256, 256);
  transpose_pad<<<tblocks((long)1*256*576),  256, 0, stream>>>(gw1, flagp, gw1t, 1, 556, 256, 576, 256);
  transpose_pad<<<tblocks((long)1*128*256),  256, 0, stream>>>(gw2, flagp, gw2t, 1, 256, 128, 256, 128);
  transpose_pad<<<tblocks((long)5*256*832),  256, 0, stream>>>(wl1, flagp, wl1t, 5, 812, 256, 832, 256);
  transpose_pad<<<tblocks((long)5*256*288),  256, 0, stream>>>(wl2, flagp, wl2t, 5, 288, 256, 288, 256);
  transpose_pad<<<tblocks((long)5*576*288),  256, 0, stream>>>(wl3, flagp, wl3t, 5, 288, 524, 288, 576);

  // ---- INet: I(2048) -> 256 -> 256 -> 256, written into h0 cols 556..811 ----
  gemm128<true><<<dim3(BATCH/128, 2), 256, 0, stream>>>(Ibf, 2048, iw1t, 2048, ib1c, i1, 256, 0,   2048);
  gemm128<true><<<dim3(BATCH/128, 2), 256, 0, stream>>>(i1,  256,  iw2t, 256,  ib2c, i2, 256, 0,   256);
  gemm128<true><<<dim3(BATCH/128, 2), 256, 0, stream>>>(i2,  256,  iw3t, 256,  ib3c, h0, 832, 556, 256);

  // ---- Gating: [z|p_prev](556, padded 576) -> 256 -> 128 -> softmax(5) ----
  gemm128<true><<<dim3(BATCH/128, 2), 256, 0, stream>>>(h0, 832, gw1t, 576, gb1c, g1, 256, 0, 576);
  gemm128<true><<<dim3(BATCH/128, 1), 256, 0, stream>>>(g1, 256, gw2t, 256, gb2c, g2, 128, 0, 256);
  gating3_kernel<<<BATCH/4, 256, 0, stream>>>(g2, gw3c, gb3c, omega);

  // ---- MoE layers ----
  moe_gemm<true><<<dim3(BATCH/64, 4), 256, 0, stream>>>(
      h0, 832, wl1t, 832, (long)256 * 832, bl1c, 256, omega, h1c, 288, 32, 256, 832, flagp, 0);
  moe_gemm<true><<<dim3(BATCH/64, 4), 256, 0, stream>>>(
      h1c, 288, wl2t, 288, (long)256 * 288, bl2c, 256, omega, h2c, 288, 32, 256, 288, flagp, 0);
  moe_gemm<false><<<dim3(BATCH/64, 9), 256, 0, stream>>>(
      h2c, 288, wl3t, 288, (long)576 * 288, bl3c, 524, omega, d_out, 524, 0, 524, 288, flagp, 1);
}